// Round 10
// baseline (141.122 us; speedup 1.0000x reference)
//
#include <hip/hip_runtime.h>
#include <stdint.h>

#define NWL 31

typedef __attribute__((ext_vector_type(8))) short short8;
typedef __attribute__((ext_vector_type(4))) float f32x4;
typedef __attribute__((ext_vector_type(4))) uint32_t u32x4;

#define WCOMP 32768                 // bytes per (layer, hi-or-lo) fragment block
#define WLAYER 65536                // hi+lo per layer
#define WS_W_BYTES (NWL * WLAYER)   // 2,031,616 B

#define LDS_ACT0 0                  // packed u32 act ping: 64 rows x 512 B
#define LDS_ACT1 32768              // pong
#define LDS_TOTAL 65536

__device__ __forceinline__ uint16_t f2bf(float f) {
  uint32_t u = __builtin_bit_cast(uint32_t, f);
  u += 0x7FFFu + ((u >> 16) & 1u);            // RNE (prep only)
  return (uint16_t)(u >> 16);
}
__device__ __forceinline__ float bf2f(uint16_t b) {
  return __builtin_bit_cast(float, (uint32_t)b << 16);
}

__device__ __forceinline__ uint32_t perm_hihi(uint32_t hi, uint32_t lo) {
#if __has_builtin(__builtin_amdgcn_perm)
  return __builtin_amdgcn_perm(hi, lo, 0x07060302u);
#else
  return (hi & 0xFFFF0000u) | (lo >> 16);
#endif
}
__device__ __forceinline__ uint32_t perm_lolo(uint32_t hi, uint32_t lo) {
#if __has_builtin(__builtin_amdgcn_perm)
  return __builtin_amdgcn_perm(hi, lo, 0x05040100u);
#else
  return (hi << 16) | (lo & 0xFFFFu);
#endif
}

// ---------------------------------------------------------------------------
// Prep (unchanged): WM = W*M -> MFMA-fragment-ordered bf16 hi/lo in ws, plus
// f32 bias. Lane holds B[k=kk*32+8*(lane>>4)+i][n=ntile*16+(lane&15)].
// ---------------------------------------------------------------------------
__global__ __launch_bounds__(512)
void prep_weights(const float* __restrict__ W, const float* __restrict__ M,
                  char* __restrict__ wsW, float* __restrict__ wsB) {
  const int l    = blockIdx.x >> 2;
  const int kk   = blockIdx.x & 3;
  const int nt   = threadIdx.x >> 6;
  const int lane = threadIdx.x & 63;
  const int kbase = kk * 32 + ((lane >> 4) << 3);
  const int n     = (nt << 4) + (lane & 15);
  const float* Wl = W + l * 129 * 128;
  const float* Ml = M + l * 129 * 128;
  short8 vh, vl;
#pragma unroll
  for (int i = 0; i < 8; ++i) {
    const int k = kbase + i;
    const float v = Wl[k * 128 + n] * Ml[k * 128 + n];
    const uint16_t h = f2bf(v);
    vh[i] = (short)h;
    vl[i] = (short)f2bf(v - bf2f(h));
  }
  char* base = wsW + l * WLAYER;
  const int frag = ((kk * 8 + nt) * 64 + lane) * 16;
  *(short8*)(base + frag)         = vh;
  *(short8*)(base + WCOMP + frag) = vl;
  if (kk == 0 && threadIdx.x < 128) {
    const int t = threadIdx.x;
    wsB[l * 128 + t] = Wl[128 * 128 + t] * Ml[128 * 128 + t];
  }
}

// ---------------------------------------------------------------------------
// Main: 256 blocks x 512 threads, 8 waves 2M x 4N (wave tile 32x32, acc[2][2]).
// REGISTER DIET -> 2 blocks/CU (R7 had ~200 unified regs = 1 block/CU,
// latency-bound at 20% occupancy). B single-buffered (64 regs) with
// same-register prefetch: B(l+1) loads issue AFTER the last MFMA use of B(l)
// (in-order issue => WAR free); flight covered by epilogue+barrier+other
// block. A addrs: 4 base regs + kk*128 immediate (XOR swizzle never touches
// kk bits). Epilogue addrs: 4 bases + 4 shared deltas (algebra verified vs
// R7's validated eoff). Act ping-pong via address-XOR flip, 1 barrier/layer.
// ---------------------------------------------------------------------------
__global__ __launch_bounds__(512, 4)
void dag_mlp(const float* __restrict__ x, const char* __restrict__ wsW,
             const float* __restrict__ wsB, float* __restrict__ out) {
  extern __shared__ char lds[];
  const int tid  = threadIdx.x;
  const int lane = tid & 63;
  const int wv   = tid >> 6;   // wave 0..7
  const int wm   = wv >> 2;    // M-half (32 rows)
  const int wn   = wv & 3;     // N-quarter (32 cols)
  const int l16  = lane & 15;
  const int g4   = lane >> 4;
  const int r0   = blockIdx.x << 6;

  // ---- x -> packed act ping (swizzled), one b128 write per 4 cols
#pragma unroll
  for (int it = 0; it < 4; ++it) {
    const int idx = tid + it * 512;       // [64 rows][32 col-quads]
    const int row = idx >> 5;
    const int cq  = idx & 31;
    const f32x4 v = *(const f32x4*)(x + (size_t)(r0 + row) * 128 + cq * 4);
    u32x4 w;
#pragma unroll
    for (int c = 0; c < 4; ++c) {
      const uint32_t u  = __builtin_bit_cast(uint32_t, v[c]);
      const float    hi = __builtin_bit_cast(float, u & 0xFFFF0000u);
      const uint32_t ur = __builtin_bit_cast(uint32_t, v[c] - hi);
      w[c] = perm_hihi(ur, u);            // lo16=hi_bf16, hi16=lo_bf16
    }
    const int off = row * 512 + ((cq ^ (row & 7)) << 4);
    *(u32x4*)(lds + LDS_ACT0 + off) = w;
  }

  // ---- A-read bases: addr = aAddr[fr][b] + kk*128 (immediate)
  int aAddr[2][2];
#pragma unroll
  for (int fr = 0; fr < 2; ++fr) {
    const int arow = wm * 32 + fr * 16 + l16;
#pragma unroll
    for (int b = 0; b < 2; ++b)
      aAddr[fr][b] = LDS_ACT0 + arow * 512 + (((g4 * 2 + b) ^ (arow & 7)) << 4);
  }
  // ---- epilogue bases + shared deltas: addr = eBase[fr][fc] + eD[i]
  int eBase[2][2], eD[4];
#pragma unroll
  for (int fr = 0; fr < 2; ++fr) {
    const int R0 = wm * 32 + fr * 16 + g4 * 4;
#pragma unroll
    for (int fc = 0; fc < 2; ++fc)
      eBase[fr][fc] = LDS_ACT1 + R0 * 512 + wn * 128 +
                      ((fc ^ (g4 & 1)) << 6) + ((l16 & 3) << 2);
  }
#pragma unroll
  for (int i = 0; i < 4; ++i)
    eD[i] = i * 512 + (((l16 >> 2) ^ i) << 4);

  const float* biasLp = wsB + wn * 32 + l16;
  const char*  wlane  = wsW + wn * 2048 + (size_t)lane * 16;

  // ---- preload layer-0 B (single buffer, 64 regs)
  u32x4 Bc[16];
#pragma unroll
  for (int kk = 0; kk < 4; ++kk)
#pragma unroll
    for (int fc = 0; fc < 2; ++fc)
#pragma unroll
      for (int hl = 0; hl < 2; ++hl)
        Bc[kk * 4 + fc * 2 + hl] =
            *(const u32x4*)(wlane + kk * 8192 + fc * 1024 + hl * 32768);

  __syncthreads();                        // act ping visible

  for (int l = 0; l < NWL; ++l) {
    const float bias0 = biasLp[l * 128];
    const float bias1 = biasLp[l * 128 + 16];
    f32x4 acc[2][2];
#pragma unroll
    for (int fr = 0; fr < 2; ++fr)
#pragma unroll
      for (int fc = 0; fc < 2; ++fc) {
        f32x4 z = {0.f, 0.f, 0.f, 0.f};
        acc[fr][fc] = z;
      }

#pragma unroll
    for (int kk = 0; kk < 4; ++kk) {
      const short8 bH0 = __builtin_bit_cast(short8, Bc[kk * 4 + 0]);
      const short8 bL0 = __builtin_bit_cast(short8, Bc[kk * 4 + 1]);
      const short8 bH1 = __builtin_bit_cast(short8, Bc[kk * 4 + 2]);
      const short8 bL1 = __builtin_bit_cast(short8, Bc[kk * 4 + 3]);
#pragma unroll
      for (int fr = 0; fr < 2; ++fr) {
        const u32x4 p0 = *(const u32x4*)(lds + aAddr[fr][0] + kk * 128);
        const u32x4 p1 = *(const u32x4*)(lds + aAddr[fr][1] + kk * 128);
        u32x4 hh, llv;
        hh[0]  = perm_lolo(p0[1], p0[0]);  hh[1]  = perm_lolo(p0[3], p0[2]);
        hh[2]  = perm_lolo(p1[1], p1[0]);  hh[3]  = perm_lolo(p1[3], p1[2]);
        llv[0] = perm_hihi(p0[1], p0[0]);  llv[1] = perm_hihi(p0[3], p0[2]);
        llv[2] = perm_hihi(p1[1], p1[0]);  llv[3] = perm_hihi(p1[3], p1[2]);
        const short8 aH = __builtin_bit_cast(short8, hh);
        const short8 aL = __builtin_bit_cast(short8, llv);
        acc[fr][0] = __builtin_amdgcn_mfma_f32_16x16x32_bf16(aH, bH0, acc[fr][0], 0, 0, 0);
        acc[fr][1] = __builtin_amdgcn_mfma_f32_16x16x32_bf16(aH, bH1, acc[fr][1], 0, 0, 0);
        acc[fr][0] = __builtin_amdgcn_mfma_f32_16x16x32_bf16(aL, bH0, acc[fr][0], 0, 0, 0);
        acc[fr][1] = __builtin_amdgcn_mfma_f32_16x16x32_bf16(aL, bH1, acc[fr][1], 0, 0, 0);
        acc[fr][0] = __builtin_amdgcn_mfma_f32_16x16x32_bf16(aH, bL0, acc[fr][0], 0, 0, 0);
        acc[fr][1] = __builtin_amdgcn_mfma_f32_16x16x32_bf16(aH, bL1, acc[fr][1], 0, 0, 0);
      }
    }

    // ---- same-register B prefetch (after last Bc use; WAR is free in-order)
    if (l + 1 < NWL) {
      const char* wl = wlane + (size_t)(l + 1) * WLAYER;
#pragma unroll
      for (int kk = 0; kk < 4; ++kk)
#pragma unroll
        for (int fc = 0; fc < 2; ++fc)
#pragma unroll
          for (int hl = 0; hl < 2; ++hl)
            Bc[kk * 4 + fc * 2 + hl] =
                *(const u32x4*)(wl + kk * 8192 + fc * 1024 + hl * 32768);
    }

    if (l == NWL - 1) {
#pragma unroll
      for (int fr = 0; fr < 2; ++fr)
#pragma unroll
        for (int fc = 0; fc < 2; ++fc) {
          const float bias = fc ? bias1 : bias0;
          const int col = wn * 32 + fc * 16 + l16;
#pragma unroll
          for (int i = 0; i < 4; ++i) {
            const int row = r0 + wm * 32 + fr * 16 + g4 * 4 + i;
            out[(size_t)row * 128 + col] = fmaxf(acc[fr][fc][i] + bias, 0.0f);
          }
        }
    } else {
#pragma unroll
      for (int fr = 0; fr < 2; ++fr)
#pragma unroll
        for (int fc = 0; fc < 2; ++fc) {
          const float bias = fc ? bias1 : bias0;
#pragma unroll
          for (int i = 0; i < 4; ++i) {
            const float v = fmaxf(acc[fr][fc][i] + bias, 0.0f);
            const uint32_t u  = __builtin_bit_cast(uint32_t, v);
            const float    hi = __builtin_bit_cast(float, u & 0xFFFF0000u);
            const uint32_t ur = __builtin_bit_cast(uint32_t, v - hi);
            *(uint32_t*)(lds + eBase[fr][fc] + eD[i]) = perm_hihi(ur, u);
          }
        }
      // flip ping-pong (address-XOR; no buffer-parity code needed)
#pragma unroll
      for (int fr = 0; fr < 2; ++fr) {
        aAddr[fr][0] ^= 32768; aAddr[fr][1] ^= 32768;
        eBase[fr][0] ^= 32768; eBase[fr][1] ^= 32768;
      }
    }
    __syncthreads();
  }
}

// ---------------------------------------------------------------------------
extern "C" void kernel_launch(void* const* d_in, const int* in_sizes, int n_in,
                              void* d_out, int out_size, void* d_ws, size_t ws_size,
                              hipStream_t stream) {
  const float* x = (const float*)d_in[0];
  const float* W = (const float*)d_in[1];
  const float* M = (const float*)d_in[2];
  char*  wsW = (char*)d_ws;
  float* wsB = (float*)((char*)d_ws + WS_W_BYTES);
  float* out = (float*)d_out;

  (void)hipFuncSetAttribute((const void*)dag_mlp,
                            hipFuncAttributeMaxDynamicSharedMemorySize, LDS_TOTAL);

  hipLaunchKernelGGL(prep_weights, dim3(NWL * 4), dim3(512), 0, stream, W, M, wsW, wsB);
  hipLaunchKernelGGL(dag_mlp, dim3(256), dim3(512), LDS_TOTAL, stream, x, wsW, wsB, out);
}